// Round 6
// baseline (487.170 us; speedup 1.0000x reference)
//
#include <hip/hip_runtime.h>
#include <hip/hip_bf16.h>

// Problem constants (static per reference)
#define NTOK 16384   // B*T
#define HD   512     // H
#define ED   8       // E experts
#define FD   2048    // F
#define CAP  5120    // capacity per expert
#define NA   32768   // NTOK * K(=2)

typedef __bf16 bf16x8 __attribute__((ext_vector_type(8)));
typedef float  f32x4  __attribute__((ext_vector_type(4)));

// Workspace layout (bytes). Total ~249 MB.
static constexpr size_t OFF_EIDX = 0;                                  // int[NA]
static constexpr size_t OFF_WGT  = 131072;                             // float[NA]
static constexpr size_t OFF_STOK = 262144;                             // int[ED*CAP]
static constexpr size_t OFF_ASLOT= 425984;                             // int[NA] (slot per assignment, -1 dropped)
static constexpr size_t OFF_ECNT = 557056;                             // int[ED] (clipped expert counts)
static constexpr size_t OFF_W2T  = 1u << 20;                           // bf16[ED][HD][FD]
static constexpr size_t OFF_H    = OFF_W2T + (size_t)ED*HD*FD*2;       // bf16[ED][CAP][FD]
static constexpr size_t OFF_W1T  = OFF_H   + (size_t)ED*CAP*FD*2;      // bf16[ED][FD][HD]
static constexpr size_t OFF_XBF  = OFF_W1T + (size_t)ED*FD*HD*2;       // bf16[NTOK][HD]
static constexpr size_t OFF_EOUT = OFF_XBF + (size_t)NTOK*HD*2;        // fp16[ED][CAP][HD]

__device__ __forceinline__ unsigned short f2bf(float f) {
    __bf16 b = (__bf16)f;
    return __builtin_bit_cast(unsigned short, b);
}
__device__ __forceinline__ unsigned short f2h(float f) {
    _Float16 h = (_Float16)f;
    return __builtin_bit_cast(unsigned short, h);
}
__device__ __forceinline__ float h2f(unsigned short u) {
    return (float)__builtin_bit_cast(_Float16, u);
}

// gelu(tanh approx) == v * sigmoid(2*0.79788456*(v + 0.044715 v^3))  (exact identity)
// v_rcp_f32 (~1ulp) instead of the exact-div sequence: invisible after bf16
// rounding (R2 post-mortem: exact-div epilogue drove VALUBusy to 56%).
__device__ __forceinline__ float gelu_fast(float v) {
    const float t = v * v;
    const float u = v * fmaf(t, 0.0713548214f, 1.5957691216f);
    const float e = __expf(-u);
    return v * __builtin_amdgcn_rcpf(1.f + e);
}

// Direct global->LDS DMA, 16B per lane. LDS dest is wave-uniform base +
// lane*16 (HW semantics, m104/m108); global src is per-lane.
__device__ __forceinline__ void gl16(const unsigned short* g, unsigned short* l) {
    __builtin_amdgcn_global_load_lds(
        (const __attribute__((address_space(1))) unsigned int*)(const void*)g,
        (__attribute__((address_space(3))) unsigned int*)(void*)l, 16, 0, 0);
}

// ---------------------------------------------------------------------------
// in: [R][C] fp32 (per expert)  ->  out: [C][R] bf16 (per expert)
// ---------------------------------------------------------------------------
__global__ __launch_bounds__(256) void transpose_cast_kernel(
    const float* __restrict__ in, unsigned short* __restrict__ out, int R, int C)
{
    __shared__ unsigned short tile[32][33];
    const int e = blockIdx.z;
    in  += (size_t)e * R * C;
    out += (size_t)e * R * C;
    const int r0 = blockIdx.y * 32, c0 = blockIdx.x * 32;
    const int tr = threadIdx.x >> 3, tc = (threadIdx.x & 7) * 4;
    const float4 v = *(const float4*)(in + (size_t)(r0 + tr) * C + c0 + tc);
    tile[tr][tc + 0] = f2bf(v.x);
    tile[tr][tc + 1] = f2bf(v.y);
    tile[tr][tc + 2] = f2bf(v.z);
    tile[tr][tc + 3] = f2bf(v.w);
    __syncthreads();
    ushort4 o;
    o.x = tile[tc + 0][tr]; o.y = tile[tc + 1][tr];
    o.z = tile[tc + 2][tr]; o.w = tile[tc + 3][tr];
    *(ushort4*)(out + (size_t)(c0 + tr) * R + r0 + tc) = o;
}

// ---------------------------------------------------------------------------
// Router (+ fused x->bf16 cast): logits = x @ router_w (fp32), top-2, softmax.
// ---------------------------------------------------------------------------
__global__ __launch_bounds__(256) void router_kernel(
    const float* __restrict__ x, const float* __restrict__ rw,
    int* __restrict__ eidx, float* __restrict__ wgt,
    unsigned short* __restrict__ xbf)
{
    __shared__ float rws[HD * ED];
    const int tid = threadIdx.x;
    for (int i = tid * 4; i < HD * ED; i += 256 * 4)
        *(float4*)(rws + i) = *(const float4*)(rw + i);
    __syncthreads();

    const int wid = tid >> 6, lane = tid & 63;
    const int t = blockIdx.x * 4 + wid;
    const float* xr = x + (size_t)t * HD;

    float acc[ED];
#pragma unroll
    for (int e = 0; e < ED; e++) acc[e] = 0.f;

    float4 xv0 = *(const float4*)(xr + lane * 8);
    float4 xv1 = *(const float4*)(xr + lane * 8 + 4);
    float xv[8] = {xv0.x, xv0.y, xv0.z, xv0.w, xv1.x, xv1.y, xv1.z, xv1.w};

    union { unsigned short us[8]; uint4 v; } pk;
#pragma unroll
    for (int j = 0; j < 8; j++) pk.us[j] = f2bf(xv[j]);
    *(uint4*)(xbf + (size_t)t * HD + lane * 8) = pk.v;

#pragma unroll
    for (int j = 0; j < 8; j++) {
        const int h = lane * 8 + j;
#pragma unroll
        for (int e = 0; e < ED; e++) acc[e] += xv[j] * rws[h * ED + e];
    }
#pragma unroll
    for (int off = 32; off >= 1; off >>= 1) {
#pragma unroll
        for (int e = 0; e < ED; e++) acc[e] += __shfl_down(acc[e], off);
    }
    if (lane == 0) {
        int e0 = 0; float l0 = acc[0];
        for (int e = 1; e < ED; e++) if (acc[e] > l0) { l0 = acc[e]; e0 = e; }
        int e1 = 0; float l1 = -1e30f;
        for (int e = 0; e < ED; e++) {
            if (e == e0) continue;
            if (acc[e] > l1) { l1 = acc[e]; e1 = e; }
        }
        const float ex = expf(l1 - l0);
        const float inv = 1.f / (1.f + ex);
        eidx[t * 2 + 0] = e0;  eidx[t * 2 + 1] = e1;
        wgt [t * 2 + 0] = inv; wgt [t * 2 + 1] = ex * inv;
    }
}

// ---------------------------------------------------------------------------
// Deterministic slot assignment (stable-sort-by-expert semantics), R6 rewrite:
// 3 passes, 2 barriers total (was: 32 rounds x 3 syncthreads + serial LDS
// prefix chains). Pass1: per-(chunk,wave,expert) ballot counts. Pass2: 8-wave
// parallel exclusive prefix over the 512 (chunk,wave) entries per expert
// (order matches assignment order (c,wid,lane) -> stable). Pass3: rank+assign.
// ---------------------------------------------------------------------------
__global__ __launch_bounds__(1024) void scan_kernel(
    const int* __restrict__ eidx,
    int* __restrict__ stok, int* __restrict__ aslot, int* __restrict__ ecnt)
{
    __shared__ int wcnt[32][16][ED];   // 16 KB
    __shared__ int woff[32][16][ED];   // 16 KB
    const int tid = threadIdx.x;
    const int lane = tid & 63, wid = tid >> 6;
    const unsigned long long below = (1ull << lane) - 1ull;

    for (int i = tid; i < ED * CAP; i += 1024) stok[i] = -1;

    // Pass 1: counts (each wave writes only its own wcnt rows; no sync needed)
    for (int c = 0; c < NA / 1024; c++) {
        const int e = eidx[c * 1024 + tid];
#pragma unroll
        for (int ee = 0; ee < ED; ee++) {
            unsigned long long m = __ballot(e == ee);
            if (lane == 0) wcnt[c][wid][ee] = __popcll(m);
        }
    }
    __syncthreads();

    // Pass 2: exclusive prefix per expert; wave w handles expert w.
    if (wid < ED) {
        const int e = wid;
        int carry = 0;
#pragma unroll
        for (int r = 0; r < 8; r++) {
            const int idx = r * 64 + lane;      // linear (c,w): c=idx>>4, w=idx&15
            const int v = wcnt[idx >> 4][idx & 15][e];
            int s = v;
#pragma unroll
            for (int off = 1; off < 64; off <<= 1) {
                int u = __shfl_up(s, off);
                if (lane >= off) s += u;
            }
            woff[idx >> 4][idx & 15][e] = carry + s - v;
            carry += __shfl(s, 63);
        }
        if (lane == 0) ecnt[e] = carry < CAP ? carry : CAP;
    }
    __syncthreads();

    // Pass 3: assign (no syncs; stok init ordered via the two barriers above)
    for (int c = 0; c < NA / 1024; c++) {
        const int a = c * 1024 + tid;
        const int e = eidx[a];
        int myrank = 0;
#pragma unroll
        for (int ee = 0; ee < ED; ee++) {
            unsigned long long m = __ballot(e == ee);
            if (ee == e) myrank = __popcll(m & below);
        }
        const int slot = woff[c][wid][e] + myrank;
        if (slot < CAP) {
            stok[e * CAP + slot] = a >> 1;   // token = a / K
            aslot[a] = slot;
        } else {
            aslot[a] = -1;                   // dropped
        }
    }
}

// ---------------------------------------------------------------------------
// MFMA GEMM, R6: register-level fragment DOUBLE-BUFFER on top of the 3-deep
// DMA pipeline. R4/R5 post-mortem: barrier/vmcnt restructuring was neutral —
// the binding constraint is the intra-phase ds_read->MFMA serial chain
// (~120cy LDS latency + 8x12cy b128 exposed every K-step; MFMA issue is only
// ~78cy -> MfmaUtil pinned at 21%). Fix: step t MFMAs tile t from reg set X
// while ds_reading tile t+1 into reg set Y (independent -> compiler
// interleaves; reads get a full MFMA phase to land). Static 2-set unroll
// (rule #20). Counted vmcnt(8) (2-step slack), peeled vm8/4/0 tail.
// s_setprio around the MFMA cluster (wave role-diversity now exists).
// Bank-conflict fix: source-side XOR swizzle (m173) — verified 0 conflicts.
// Operands SWAPPED (mfma(bfv, af)): D col -> m, row -> n => ushort4 stores.
// NOTE (R1): no min-waves floor in __launch_bounds__ (acc spill disaster).
// G1=true : hout = gelu(gather(x) @ B + bias)  [bf16]
// G1=false: hout = A @ B + bias                [fp16] (combined later)
// ---------------------------------------------------------------------------
template<int KD, int ND, int NT, bool G1>
__global__ __launch_bounds__(256) void gemm_mfma(
    const unsigned short* __restrict__ Abase,
    const unsigned short* __restrict__ Bt,
    const float* __restrict__ bias,
    const int* __restrict__ stok,
    const int* __restrict__ ecnt,
    unsigned short* __restrict__ hout)
{
    constexpr int BUFE = 128 * 32;            // 4096 elems = 8 KB per buf
    constexpr int NTK  = KD / 32;             // K-tiles (16 or 64)
    __shared__ __align__(16) unsigned short As[3 * BUFE];
    __shared__ __align__(16) unsigned short Bs[3 * BUFE];

    const int tid = threadIdx.x;
    const int e  = blockIdx.x & 7;            // expert == XCD (id%8 round-robin)
    const int g  = blockIdx.x >> 3;
    const int n0 = (g % NT) * 128;            // n fastest: reuse gathered A in L2
    const int m0 = (g / NT) * 128;

    if (m0 >= ecnt[e]) return;                // capacity-padding tile: skip

    const int lane = tid & 63;
    const int wid  = tid >> 6;

    // Staging map: wave w, instr p covers rows [(2w+p)*16, +16); lane ->
    // (row sub = lane>>2, chunk = lane&3). Global source chunk is XOR-swizzled.
    const int rsub = lane >> 2;                       // 0..15
    const int csw  = (lane & 3) ^ ((rsub >> 1) & 3);  // pre-swizzled src chunk

    const unsigned short *ag0, *ag1, *bg0, *bg1;
    {
        const int R0 = (wid * 2 + 0) * 16 + rsub;
        const int R1 = (wid * 2 + 1) * 16 + rsub;
        size_t a0, a1;
        if constexpr (G1) {
            const int t0 = stok[e * CAP + m0 + R0];
            const int t1 = stok[e * CAP + m0 + R1];
            a0 = (size_t)(t0 >= 0 ? t0 : 0);   // dropped -> row 0 (never read back)
            a1 = (size_t)(t1 >= 0 ? t1 : 0);
        } else {
            a0 = (size_t)(e * CAP + m0 + R0);
            a1 = (size_t)(e * CAP + m0 + R1);
        }
        ag0 = Abase + a0 * KD + csw * 8;
        ag1 = Abase + a1 * KD + csw * 8;
        bg0 = Bt + ((size_t)e * ND + n0 + R0) * KD + csw * 8;
        bg1 = Bt + ((size_t)e * ND + n0 + R1) * KD + csw * 8;
    }
    unsigned short* lA = As + (wid * 2) * 512;  // wave-uniform DMA dest bases
    unsigned short* lB = Bs + (wid * 2) * 512;

    const int wrow = (wid & 1) * 64;
    const int wcol = (wid >> 1) * 64;
    const int l15  = lane & 15;
    const int quad = lane >> 4;
    const int xq   = quad ^ ((l15 >> 1) & 3);   // read-side XOR (row>>1 & 3)
    const int fA   = (wrow + l15) * 32 + xq * 8;
    const int fB   = (wcol + l15) * 32 + xq * 8;

    f32x4 acc[4][4];
#pragma unroll
    for (int i = 0; i < 4; i++)
#pragma unroll
        for (int j = 0; j < 4; j++) acc[i][j] = (f32x4)0.f;

    bf16x8 afA[4], bfA[4], afB[4], bfB[4];    // two static fragment sets

#define STAGE(SO, KC)                                                          \
    {                                                                          \
        gl16(ag0 + (KC), lA + (SO));                                           \
        gl16(ag1 + (KC), lA + (SO) + 512);                                     \
        gl16(bg0 + (KC), lB + (SO));                                           \
        gl16(bg1 + (KC), lB + (SO) + 512);                                     \
    }

#define DSREAD(RA, RB, SO)                                                     \
    {                                                                          \
        _Pragma("unroll")                                                      \
        for (int i = 0; i < 4; i++) RA[i] = *(const bf16x8*)(As + (SO) + fA + i * 512); \
        _Pragma("unroll")                                                      \
        for (int j = 0; j < 4; j++) RB[j] = *(const bf16x8*)(Bs + (SO) + fB + j * 512); \
    }

// Swapped-operand MFMA: D = bfv x af -> col(lane&15) indexes m, row indexes n.
#define MFMA16(RA, RB)                                                         \
    {                                                                          \
        __builtin_amdgcn_s_setprio(1);                                         \
        _Pragma("unroll")                                                      \
        for (int i = 0; i < 4; i++)                                            \
            _Pragma("unroll")                                                  \
            for (int j = 0; j < 4; j++)                                        \
                acc[i][j] = __builtin_amdgcn_mfma_f32_16x16x32_bf16(           \
                    RB[j], RA[i], acc[i][j], 0, 0, 0);                         \
        __builtin_amdgcn_s_setprio(0);                                         \
    }

#define CLOSE_STEP                                                             \
    asm volatile("s_waitcnt lgkmcnt(0)" ::: "memory");                         \
    __builtin_amdgcn_s_barrier();                                              \
    asm volatile("" ::: "memory");

#define OPEN_STEP(VMSTR)                                                       \
    asm volatile(VMSTR ::: "memory");                                          \
    __builtin_amdgcn_s_barrier();                                              \
    asm volatile("" ::: "memory");

    // Prologue: 3 tiles in flight; read tile 0 into set A.
    STAGE(0, 0);
    STAGE(BUFE, 32);
    STAGE(2 * BUFE, 64);
    OPEN_STEP("s_waitcnt vmcnt(8)");          // tile 0 landed (everyone)
    DSREAD(afA, bfA, 0);
    CLOSE_STEP                                 // slot 0 free for re-stage

    int sSt = 0;            // stage slot at step t  = slot(t%3)
    int sRd = BUFE;         // read  slot at step t  = slot((t+1)%3)
    int kcS = 96;           // tile t+3 K-offset
    for (int t = 0; t <= NTK - 6; t += 2) {
        // even step t: MFMA set A (tile t), read tile t+1 -> set B
        STAGE(sSt, kcS);
        OPEN_STEP("s_waitcnt vmcnt(8)");
        DSREAD(afB, bfB, sRd);
        MFMA16(afA, bfA);
        CLOSE_STEP
        sSt = (sSt == 2 * BUFE) ? 0 : sSt + BUFE;
        sRd = (sRd == 2 * BUFE) ? 0 : sRd + BUFE;
        kcS += 32;
        // odd step t+1: MFMA set B, read tile t+2 -> set A
        STAGE(sSt, kcS);
        OPEN_STEP("s_waitcnt vmcnt(8)");
        DSREAD(afA, bfA, sRd);
        MFMA16(afB, bfB);
        CLOSE_STEP
        sSt = (sSt == 2 * BUFE) ? 0 : sSt + BUFE;
        sRd = (sRd == 2 * BUFE) ? 0 : sRd + BUFE;
        kcS += 32;
    }
    // Peeled t = NTK-4 (even): last STAGE (tile NTK-1), vm8
    STAGE(sSt, (NTK - 1) * 32);
    OPEN_STEP("s_waitcnt vmcnt(8)");
    DSREAD(afB, bfB, sRd);
    MFMA16(afA, bfA);
    CLOSE_STEP
    sRd = (sRd == 2 * BUFE) ? 0 : sRd + BUFE;
    // Peeled t = NTK-3 (odd): no STAGE, vm4
    OPEN_STEP("s_waitcnt vmcnt(4)");
    DSREAD(afA, bfA, sRd);
    MFMA16(afB, bfB);
    CLOSE_STEP
    sRd = (sRd == 2 * BUFE) ? 0 : sRd + BUFE;
    // Peeled t = NTK-2 (even): no STAGE, vm0
    OPEN_STEP("s_waitcnt vmcnt(0)");
    DSREAD(afB, bfB, sRd);
    MFMA16(afA, bfA);
    CLOSE_STEP
    // Peeled t = NTK-1 (odd): MFMA only
    MFMA16(afB, bfB);
#undef STAGE
#undef DSREAD
#undef MFMA16
#undef CLOSE_STEP
#undef OPEN_STEP

    // Epilogue (transposed D): m = wrow + i*16 + l15, n = wcol + j*16 + quad*4
    // + g2 -> 4 consecutive n per (i,j) -> one ushort4 store each.
#pragma unroll
    for (int i = 0; i < 4; i++) {
        unsigned short* hrow = hout
            + ((size_t)e * CAP + m0 + wrow + i * 16 + l15) * ND
            + n0 + wcol + quad * 4;
#pragma unroll
        for (int j = 0; j < 4; j++) {
            const float4 b4 = *(const float4*)(
                bias + (size_t)e * ND + n0 + wcol + j * 16 + quad * 4);
            const float v0 = acc[i][j][0] + b4.x;
            const float v1 = acc[i][j][1] + b4.y;
            const float v2 = acc[i][j][2] + b4.z;
            const float v3 = acc[i][j][3] + b4.w;
            ushort4 o;
            if constexpr (G1) {
                o.x = f2bf(gelu_fast(v0)); o.y = f2bf(gelu_fast(v1));
                o.z = f2bf(gelu_fast(v2)); o.w = f2bf(gelu_fast(v3));
            } else {
                o.x = f2h(v0); o.y = f2h(v1); o.z = f2h(v2); o.w = f2h(v3);
            }
            *(ushort4*)(hrow + j * 16) = o;
        }
    }
}

// ---------------------------------------------------------------------------
// Combine: out[t] = sum_k wgt[t,k] * eout[eidx[t,k], aslot[t,k]]  (no atomics,
// fully coalesced; writes every output element so no memset needed).
// ---------------------------------------------------------------------------
__global__ __launch_bounds__(256) void combine_kernel(
    const unsigned short* __restrict__ eout,
    const int* __restrict__ eidx, const int* __restrict__ aslot,
    const float* __restrict__ wgt, float* __restrict__ out)
{
    const int tid = threadIdx.x;
    const int t  = blockIdx.x * 2 + (tid >> 7);   // 128 threads per token
    const int h0 = (tid & 127) * 4;
    float r0 = 0.f, r1 = 0.f, r2 = 0.f, r3 = 0.f;
#pragma unroll
    for (int k = 0; k < 2; k++) {
        const int a = t * 2 + k;
        const int s = aslot[a];
        if (s >= 0) {
            const float w = wgt[a];
            const int e = eidx[a];
            const ushort4 v = *(const ushort4*)(eout + ((size_t)e * CAP + s) * HD + h0);
            r0 += w * h2f(v.x); r1 += w * h2f(v.y);
            r2 += w * h2f(v.z); r3 += w * h2f(v.w);
        }
    }
    float4 o; o.x = r0; o.y = r1; o.z = r2; o.w = r3;
    *(float4*)(out + (size_t)t * HD + h0) = o;
}

extern "C" void kernel_launch(void* const* d_in, const int* in_sizes, int n_in,
                              void* d_out, int out_size, void* d_ws, size_t ws_size,
                              hipStream_t stream)
{
    const float* x  = (const float*)d_in[0];
    const float* rw = (const float*)d_in[1];
    const float* w1 = (const float*)d_in[2];
    const float* b1 = (const float*)d_in[3];
    const float* w2 = (const float*)d_in[4];
    const float* b2 = (const float*)d_in[5];
    float* out = (float*)d_out;

    char* ws = (char*)d_ws;
    int*   eidx  = (int*)  (ws + OFF_EIDX);
    float* wgt   = (float*)(ws + OFF_WGT);
    int*   stok  = (int*)  (ws + OFF_STOK);
    int*   aslot = (int*)  (ws + OFF_ASLOT);
    int*   ecnt  = (int*)  (ws + OFF_ECNT);
    unsigned short* w2t  = (unsigned short*)(ws + OFF_W2T);
    unsigned short* hbuf = (unsigned short*)(ws + OFF_H);
    unsigned short* w1t  = (unsigned short*)(ws + OFF_W1T);
    unsigned short* xbf  = (unsigned short*)(ws + OFF_XBF);
    unsigned short* eout = (unsigned short*)(ws + OFF_EOUT);

    transpose_cast_kernel<<<dim3(FD / 32, HD / 32, ED), 256, 0, stream>>>(w1, w1t, HD, FD);
    transpose_cast_kernel<<<dim3(HD / 32, FD / 32, ED), 256, 0, stream>>>(w2, w2t, FD, HD);
    router_kernel<<<NTOK / 4, 256, 0, stream>>>(x, rw, eidx, wgt, xbf);
    scan_kernel<<<1, 1024, 0, stream>>>(eidx, stok, aslot, ecnt);

    // GEMM1: h = gelu(gather(x) @ w1 + b1)  [bf16]
    gemm_mfma<HD, FD, FD/128, true>
        <<<8 * (FD/128) * (CAP/128), 256, 0, stream>>>(
        xbf, w1t, b1, stok, ecnt, hbuf);

    // GEMM2: eout = h @ w2 + b2  [fp16, per-slot]
    gemm_mfma<FD, HD, HD/128, false>
        <<<8 * (HD/128) * (CAP/128), 256, 0, stream>>>(
        hbuf, w2t, b2, nullptr, ecnt, eout);

    // Weighted scatter-free combine (writes all tokens; replaces memset+atomics)
    combine_kernel<<<NTOK / 2, 256, 0, stream>>>(eout, eidx, aslot, wgt, out);
}

// Round 8
// 484.568 us; speedup vs baseline: 1.0054x; 1.0054x over previous
//
#include <hip/hip_runtime.h>
#include <hip/hip_bf16.h>

// Problem constants (static per reference)
#define NTOK 16384   // B*T
#define HD   512     // H
#define ED   8       // E experts
#define FD   2048    // F
#define CAP  5120    // capacity per expert
#define NA   32768   // NTOK * K(=2)

typedef __bf16 bf16x8 __attribute__((ext_vector_type(8)));
typedef float  f32x4  __attribute__((ext_vector_type(4)));

// Workspace layout (bytes). Total ~249 MB.
static constexpr size_t OFF_EIDX = 0;                                  // int[NA]
static constexpr size_t OFF_WGT  = 131072;                             // float[NA]
static constexpr size_t OFF_STOK = 262144;                             // int[ED*CAP]
static constexpr size_t OFF_ASLOT= 425984;                             // int[NA]
static constexpr size_t OFF_ECNT = 557056;                             // int[ED]
static constexpr size_t OFF_W2T  = 1u << 20;                           // bf16[ED][HD][FD]
static constexpr size_t OFF_H    = OFF_W2T + (size_t)ED*HD*FD*2;       // bf16[ED][CAP][FD]
static constexpr size_t OFF_W1T  = OFF_H   + (size_t)ED*CAP*FD*2;      // bf16[ED][FD][HD]
static constexpr size_t OFF_XBF  = OFF_W1T + (size_t)ED*FD*HD*2;       // bf16[NTOK][HD]
static constexpr size_t OFF_EOUT = OFF_XBF + (size_t)NTOK*HD*2;        // fp16[ED][CAP][HD]

__device__ __forceinline__ unsigned short f2bf(float f) {
    __bf16 b = (__bf16)f;
    return __builtin_bit_cast(unsigned short, b);
}
__device__ __forceinline__ unsigned short f2h(float f) {
    _Float16 h = (_Float16)f;
    return __builtin_bit_cast(unsigned short, h);
}
__device__ __forceinline__ float h2f(unsigned short u) {
    return (float)__builtin_bit_cast(_Float16, u);
}

// gelu(tanh approx) == v * sigmoid(2*0.79788456*(v + 0.044715 v^3))
__device__ __forceinline__ float gelu_fast(float v) {
    const float t = v * v;
    const float u = v * fmaf(t, 0.0713548214f, 1.5957691216f);
    const float e = __expf(-u);
    return v * __builtin_amdgcn_rcpf(1.f + e);
}

// Direct global->LDS DMA, 16B per lane (dest = wave-uniform base + lane*16).
__device__ __forceinline__ void gl16(const unsigned short* g, unsigned short* l) {
    __builtin_amdgcn_global_load_lds(
        (const __attribute__((address_space(1))) unsigned int*)(const void*)g,
        (__attribute__((address_space(3))) unsigned int*)(void*)l, 16, 0, 0);
}

// ---------------------------------------------------------------------------
// in: [R][C] fp32 (per expert)  ->  out: [C][R] bf16 (per expert)
// ---------------------------------------------------------------------------
__global__ __launch_bounds__(256) void transpose_cast_kernel(
    const float* __restrict__ in, unsigned short* __restrict__ out, int R, int C)
{
    __shared__ unsigned short tile[32][33];
    const int e = blockIdx.z;
    in  += (size_t)e * R * C;
    out += (size_t)e * R * C;
    const int r0 = blockIdx.y * 32, c0 = blockIdx.x * 32;
    const int tr = threadIdx.x >> 3, tc = (threadIdx.x & 7) * 4;
    const float4 v = *(const float4*)(in + (size_t)(r0 + tr) * C + c0 + tc);
    tile[tr][tc + 0] = f2bf(v.x);
    tile[tr][tc + 1] = f2bf(v.y);
    tile[tr][tc + 2] = f2bf(v.z);
    tile[tr][tc + 3] = f2bf(v.w);
    __syncthreads();
    ushort4 o;
    o.x = tile[tc + 0][tr]; o.y = tile[tc + 1][tr];
    o.z = tile[tc + 2][tr]; o.w = tile[tc + 3][tr];
    *(ushort4*)(out + (size_t)(c0 + tr) * R + r0 + tc) = o;
}

// ---------------------------------------------------------------------------
// Router (+ fused x->bf16 cast)
// ---------------------------------------------------------------------------
__global__ __launch_bounds__(256) void router_kernel(
    const float* __restrict__ x, const float* __restrict__ rw,
    int* __restrict__ eidx, float* __restrict__ wgt,
    unsigned short* __restrict__ xbf)
{
    __shared__ float rws[HD * ED];
    const int tid = threadIdx.x;
    for (int i = tid * 4; i < HD * ED; i += 256 * 4)
        *(float4*)(rws + i) = *(const float4*)(rw + i);
    __syncthreads();

    const int wid = tid >> 6, lane = tid & 63;
    const int t = blockIdx.x * 4 + wid;
    const float* xr = x + (size_t)t * HD;

    float acc[ED];
#pragma unroll
    for (int e = 0; e < ED; e++) acc[e] = 0.f;

    float4 xv0 = *(const float4*)(xr + lane * 8);
    float4 xv1 = *(const float4*)(xr + lane * 8 + 4);
    float xv[8] = {xv0.x, xv0.y, xv0.z, xv0.w, xv1.x, xv1.y, xv1.z, xv1.w};

    union { unsigned short us[8]; uint4 v; } pk;
#pragma unroll
    for (int j = 0; j < 8; j++) pk.us[j] = f2bf(xv[j]);
    *(uint4*)(xbf + (size_t)t * HD + lane * 8) = pk.v;

#pragma unroll
    for (int j = 0; j < 8; j++) {
        const int h = lane * 8 + j;
#pragma unroll
        for (int e = 0; e < ED; e++) acc[e] += xv[j] * rws[h * ED + e];
    }
#pragma unroll
    for (int off = 32; off >= 1; off >>= 1) {
#pragma unroll
        for (int e = 0; e < ED; e++) acc[e] += __shfl_down(acc[e], off);
    }
    if (lane == 0) {
        int e0 = 0; float l0 = acc[0];
        for (int e = 1; e < ED; e++) if (acc[e] > l0) { l0 = acc[e]; e0 = e; }
        int e1 = 0; float l1 = -1e30f;
        for (int e = 0; e < ED; e++) {
            if (e == e0) continue;
            if (acc[e] > l1) { l1 = acc[e]; e1 = e; }
        }
        const float ex = expf(l1 - l0);
        const float inv = 1.f / (1.f + ex);
        eidx[t * 2 + 0] = e0;  eidx[t * 2 + 1] = e1;
        wgt [t * 2 + 0] = inv; wgt [t * 2 + 1] = ex * inv;
    }
}

// ---------------------------------------------------------------------------
// Deterministic slot assignment (stable-sort-by-expert), parallel 3-pass scan.
// ---------------------------------------------------------------------------
__global__ __launch_bounds__(1024) void scan_kernel(
    const int* __restrict__ eidx,
    int* __restrict__ stok, int* __restrict__ aslot, int* __restrict__ ecnt)
{
    __shared__ int wcnt[32][16][ED];
    __shared__ int woff[32][16][ED];
    const int tid = threadIdx.x;
    const int lane = tid & 63, wid = tid >> 6;
    const unsigned long long below = (1ull << lane) - 1ull;

    for (int i = tid; i < ED * CAP; i += 1024) stok[i] = -1;

    for (int c = 0; c < NA / 1024; c++) {
        const int e = eidx[c * 1024 + tid];
#pragma unroll
        for (int ee = 0; ee < ED; ee++) {
            unsigned long long m = __ballot(e == ee);
            if (lane == 0) wcnt[c][wid][ee] = __popcll(m);
        }
    }
    __syncthreads();

    if (wid < ED) {
        const int e = wid;
        int carry = 0;
#pragma unroll
        for (int r = 0; r < 8; r++) {
            const int idx = r * 64 + lane;
            const int v = wcnt[idx >> 4][idx & 15][e];
            int s = v;
#pragma unroll
            for (int off = 1; off < 64; off <<= 1) {
                int u = __shfl_up(s, off);
                if (lane >= off) s += u;
            }
            woff[idx >> 4][idx & 15][e] = carry + s - v;
            carry += __shfl(s, 63);
        }
        if (lane == 0) ecnt[e] = carry < CAP ? carry : CAP;
    }
    __syncthreads();

    for (int c = 0; c < NA / 1024; c++) {
        const int a = c * 1024 + tid;
        const int e = eidx[a];
        int myrank = 0;
#pragma unroll
        for (int ee = 0; ee < ED; ee++) {
            unsigned long long m = __ballot(e == ee);
            if (ee == e) myrank = __popcll(m & below);
        }
        const int slot = woff[c][wid][e] + myrank;
        if (slot < CAP) {
            stok[e * CAP + slot] = a >> 1;
            aslot[a] = slot;
        } else {
            aslot[a] = -1;
        }
    }
}

// ---------------------------------------------------------------------------
// 256x256 / BK=64 / 8-wave / 4-phase-per-K-tile MFMA GEMM (m201-class).
// R7 post-mortem (race found by audit): per-wave reads touch rows of staging
// half (wm for A, wn>>1 for B) for BOTH quadrant indices, so P4's reads
// collectively need ALL FOUR halves of tile G+1 landed. R7 staged B-hi(G+1)
// at P3(G) -> still in flight at P4(G) under vmcnt(2) -> waves 4-7 read
// unlanded LDS. Fixed stage schedule (B-hi shifted one group earlier):
//   P1: A-hi(G+1)   P2: B-lo(G+1)   P3: B-hi(G+2)   P4: A-lo(G+2)
// At P4(G): outstanding = [B-hi(G+1), A-lo(G+1), A-hi(G+1), B-lo(G+1),
// B-hi(G+2)] = 10 loads; vmcnt(2) forces oldest 8 = ALL of tile G+1; only
// B-hi(G+2) stays in flight (counted, never drains to 0 in-loop — T4).
// Overwrite safety (re-derived): B(G) regions last READ at P1(G), consumed by
// P2's MFMA -> reads complete before P3(G)'s barrier -> P3's store into the
// same dbuf is legal; A(G) regions free after P4(G)'s barrier. Single bL
// fragment set: P4 runs MFMA(1,0,aHI,bL) BEFORE RD_B overwrites bL (WAR on
// registers keeps order). Final vmcnt(0) drain before epilogue (a block must
// not retire with in-flight DMA writing its LDS — successor-block corruption).
// XOR swizzle LDS[r][c]=global[r][c^(r&7)] -> conflict-free b128 reads,
// linear DMA writes. setprio(1) around MFMA clusters (T5).
// LDS 128 KB -> 1 block/CU; ~247 VGPR (8 waves = 2/SIMD caps at 256).
// G1=true : hout = gelu(gather(x) @ B + bias)  [bf16]
// G1=false: hout = A @ B + bias                [fp16]
// ---------------------------------------------------------------------------
template<int KD, int ND, int NTN, bool G1>
__global__ __launch_bounds__(512) void gemm_mfma(
    const unsigned short* __restrict__ Abase,
    const unsigned short* __restrict__ Bt,
    const float* __restrict__ bias,
    const int* __restrict__ stok,
    const int* __restrict__ ecnt,
    unsigned short* __restrict__ hout)
{
    constexpr int NTK = KD / 64;              // K-tiles (8 or 32), even
    // [dbuf2][half2][128 rows][64 k] per matrix, 64 KB each
    __shared__ __align__(16) unsigned short As[2 * 2 * 128 * 64];
    __shared__ __align__(16) unsigned short Bs[2 * 2 * 128 * 64];

    const int tid = threadIdx.x;
    const int e  = blockIdx.x & 7;            // expert == XCD
    const int g  = blockIdx.x >> 3;
    const int n0 = (g % NTN) * 256;
    const int m0 = (g / NTN) * 256;

    if (m0 >= ecnt[e]) return;                // padding tile: exit pre-barrier

    const int lane = tid & 63, wid = tid >> 6;
    const int wm = wid & 1, wn = wid >> 1;    // wave panel: rows wm*128, cols wn*64

    // ---- staging: half h, instr p covers rows h*128+(wid*2+p)*8+srow
    const int srow = lane >> 3;                       // 0..7
    const int csw  = ((lane & 7) ^ srow) * 8;         // pre-swizzled src chunk (elems)
    unsigned int aOff[2][2], bOff[2][2];
#pragma unroll
    for (int h = 0; h < 2; h++) {
#pragma unroll
        for (int p = 0; p < 2; p++) {
            const int R = h * 128 + (wid * 2 + p) * 8 + srow;
            unsigned int arow;
            if constexpr (G1) {
                const int t = stok[e * CAP + m0 + R];
                arow = (unsigned int)(t >= 0 ? t : 0);
            } else {
                arow = (unsigned int)(e * CAP + m0 + R);
            }
            aOff[h][p] = arow * KD + csw;
            bOff[h][p] = (unsigned int)((e * ND + n0 + R) * KD) + csw;
        }
    }

    // ---- ds_read bases (elems). LDS[r][c] holds global chunk c^(r&7).
    const int l15 = lane & 15, quad = lane >> 4;
    const int x0  = quad ^ (l15 & 7);                 // swizzled chunk for k-slice 0
    const int aRd = wm * 8192 + l15 * 64 + x0 * 8;
    const int bRd = (wn >> 1) * 8192 + (wn & 1) * 4096 + l15 * 64 + x0 * 8;

    f32x4 acc[8][4];
#pragma unroll
    for (int i = 0; i < 8; i++)
#pragma unroll
        for (int j = 0; j < 4; j++) acc[i][j] = (f32x4)0.f;

    bf16x8 aLO[4][2], aHI[4][2], bHIr[2][2], bL[2][2];

#define FENCE asm volatile("" ::: "memory")
#define BARR  { FENCE; __builtin_amdgcn_s_barrier(); FENCE; }

#define ST_A(D, H, KC)                                                         \
    { gl16(Abase + aOff[H][0] + (KC), As + ((D)*2+(H))*8192 + (wid*2+0)*512);  \
      gl16(Abase + aOff[H][1] + (KC), As + ((D)*2+(H))*8192 + (wid*2+1)*512); }
#define ST_B(D, H, KC)                                                         \
    { gl16(Bt + bOff[H][0] + (KC), Bs + ((D)*2+(H))*8192 + (wid*2+0)*512);     \
      gl16(Bt + bOff[H][1] + (KC), Bs + ((D)*2+(H))*8192 + (wid*2+1)*512); }

#define RD_A(DST, D, QM)                                                       \
    { _Pragma("unroll")                                                        \
      for (int f = 0; f < 4; f++) {                                            \
        DST[f][0] = *(const bf16x8*)(As + (D)*16384 + (QM)*4096 + f*1024 + aRd);        \
        DST[f][1] = *(const bf16x8*)(As + (D)*16384 + (QM)*4096 + f*1024 + (aRd^32)); } }
#define RD_B(DST, D, QN)                                                       \
    { _Pragma("unroll")                                                        \
      for (int j = 0; j < 2; j++) {                                            \
        DST[j][0] = *(const bf16x8*)(Bs + (D)*16384 + (QN)*2048 + j*1024 + bRd);        \
        DST[j][1] = *(const bf16x8*)(Bs + (D)*16384 + (QN)*2048 + j*1024 + (bRd^32)); } }

// Swapped operands: D col(lane&15)->m, row->n (R4-verified epilogue layout)
#define MFMA16(QM, QN, AF, BF)                                                 \
    { __builtin_amdgcn_s_setprio(1);                                           \
      _Pragma("unroll")                                                        \
      for (int fi = 0; fi < 4; fi++)                                           \
        _Pragma("unroll")                                                      \
        for (int fj = 0; fj < 2; fj++) {                                       \
            acc[(QM)*4+fi][(QN)*2+fj] = __builtin_amdgcn_mfma_f32_16x16x32_bf16( \
                BF[fj][0], AF[fi][0], acc[(QM)*4+fi][(QN)*2+fj], 0, 0, 0);     \
            acc[(QM)*4+fi][(QN)*2+fj] = __builtin_amdgcn_mfma_f32_16x16x32_bf16( \
                BF[fj][1], AF[fi][1], acc[(QM)*4+fi][(QN)*2+fj], 0, 0, 0);     \
        }                                                                      \
      __builtin_amdgcn_s_setprio(0); }

// One K-tile group (4 phases). D = dbuf of tile G.
// Stage: P1 A-hi(G+1), P2 B-lo(G+1), P3 B-hi(G+2), P4 A-lo(G+2).
#define GROUP(D, KC1, KC2)                                                     \
    /* P1 */ BARR;                                                             \
    RD_B(bHIr, (D), 1);                                                        \
    ST_A(1-(D), 1, (KC1));                                                     \
    MFMA16(0, 0, aLO, bL);                                                     \
    /* P2 */ BARR;                                                             \
    RD_A(aHI, (D), 1);                                                         \
    ST_B(1-(D), 0, (KC1));                                                     \
    MFMA16(0, 1, aLO, bHIr);                                                   \
    /* P3 */ BARR;                                                             \
    ST_B((D), 1, (KC2));                                                       \
    MFMA16(1, 1, aHI, bHIr);                                                   \
    /* P4 */ asm volatile("s_waitcnt vmcnt(2)" ::: "memory");                  \
    BARR;                                                                      \
    RD_A(aLO, 1-(D), 0);                                                       \
    ST_A((D), 0, (KC2));                                                       \
    MFMA16(1, 0, aHI, bL);                                                     \
    RD_B(bL, 1-(D), 0);

    // Prologue: tile 0 (4 halves) + B-hi(1) + A-lo(1); vmcnt(4) -> tile 0
    // fully landed (oldest 8 of 12), [B-hi1, A-lo1] = 4 stay in flight.
    ST_A(0, 0, 0);
    ST_A(0, 1, 0);
    ST_B(0, 0, 0);
    ST_B(0, 1, 0);
    ST_B(1, 1, 64);   // B-hi(1)
    ST_A(1, 0, 64);   // A-lo(1)
    asm volatile("s_waitcnt vmcnt(4)" ::: "memory");
    BARR;
    RD_A(aLO, 0, 0);
    RD_B(bL, 0, 0);

#pragma unroll 1
    for (int G = 0; G < NTK; G += 2) {
        const int t1 = G + 1;                                   // < NTK
        const int t2 = (G + 2 >= NTK) ? 0 : G + 2;              // wrap at tail
        const int t3 = (G + 3 >= NTK) ? G + 3 - NTK : G + 3;
        GROUP(0, t1 * 64, t2 * 64)
        GROUP(1, t2 * 64, t3 * 64)
    }
    // Drain: a block must not retire with DMA still writing its LDS.
    asm volatile("s_waitcnt vmcnt(0)" ::: "memory");
#undef GROUP
#undef MFMA16
#undef RD_A
#undef RD_B
#undef ST_A
#undef ST_B
#undef BARR
#undef FENCE

    // Epilogue (transposed D): m = wm*128 + i*16 + l15, n = wn*64 + j*16 +
    // quad*4 + g2 -> one ushort4 store per (i,j).
    float4 bb4[4];
#pragma unroll
    for (int j = 0; j < 4; j++)
        bb4[j] = *(const float4*)(bias + (size_t)e * ND + n0 + wn * 64 + j * 16 + quad * 4);
#pragma unroll
    for (int i = 0; i < 8; i++) {
        unsigned short* hrow = hout
            + ((size_t)e * CAP + m0 + wm * 128 + i * 16 + l15) * ND
            + n0 + wn * 64 + quad * 4;
#pragma unroll
        for (int j = 0; j < 4; j++) {
            const float v0 = acc[i][j][0] + bb4[j].x;
            const float v1 = acc[i][j][1] + bb4[j].y;
            const float v2 = acc[i][j][2] + bb4[j].z;
            const float v3 = acc[i][j][3] + bb4[j].w;
            ushort4 o;
            if constexpr (G1) {
                o.x = f2bf(gelu_fast(v0)); o.y = f2bf(gelu_fast(v1));
                o.z = f2bf(gelu_fast(v2)); o.w = f2bf(gelu_fast(v3));
            } else {
                o.x = f2h(v0); o.y = f2h(v1); o.z = f2h(v2); o.w = f2h(v3);
            }
            *(ushort4*)(hrow + j * 16) = o;
        }
    }
}

// ---------------------------------------------------------------------------
// Combine: out[t] = sum_k wgt[t,k] * eout[eidx[t,k], aslot[t,k]]
// ---------------------------------------------------------------------------
__global__ __launch_bounds__(256) void combine_kernel(
    const unsigned short* __restrict__ eout,
    const int* __restrict__ eidx, const int* __restrict__ aslot,
    const float* __restrict__ wgt, float* __restrict__ out)
{
    const int tid = threadIdx.x;
    const int t  = blockIdx.x * 2 + (tid >> 7);
    const int h0 = (tid & 127) * 4;
    float r0 = 0.f, r1 = 0.f, r2 = 0.f, r3 = 0.f;
#pragma unroll
    for (int k = 0; k < 2; k++) {
        const int a = t * 2 + k;
        const int s = aslot[a];
        if (s >= 0) {
            const float w = wgt[a];
            const int e = eidx[a];
            const ushort4 v = *(const ushort4*)(eout + ((size_t)e * CAP + s) * HD + h0);
            r0 += w * h2f(v.x); r1 += w * h2f(v.y);
            r2 += w * h2f(v.z); r3 += w * h2f(v.w);
        }
    }
    float4 o; o.x = r0; o.y = r1; o.z = r2; o.w = r3;
    *(float4*)(out + (size_t)t * HD + h0) = o;
}

extern "C" void kernel_launch(void* const* d_in, const int* in_sizes, int n_in,
                              void* d_out, int out_size, void* d_ws, size_t ws_size,
                              hipStream_t stream)
{
    const float* x  = (const float*)d_in[0];
    const float* rw = (const float*)d_in[1];
    const float* w1 = (const float*)d_in[2];
    const float* b1 = (const float*)d_in[3];
    const float* w2 = (const float*)d_in[4];
    const float* b2 = (const float*)d_in[5];
    float* out = (float*)d_out;

    char* ws = (char*)d_ws;
    int*   eidx  = (int*)  (ws + OFF_EIDX);
    float* wgt   = (float*)(ws + OFF_WGT);
    int*   stok  = (int*)  (ws + OFF_STOK);
    int*   aslot = (int*)  (ws + OFF_ASLOT);
    int*   ecnt  = (int*)  (ws + OFF_ECNT);
    unsigned short* w2t  = (unsigned short*)(ws + OFF_W2T);
    unsigned short* hbuf = (unsigned short*)(ws + OFF_H);
    unsigned short* w1t  = (unsigned short*)(ws + OFF_W1T);
    unsigned short* xbf  = (unsigned short*)(ws + OFF_XBF);
    unsigned short* eout = (unsigned short*)(ws + OFF_EOUT);

    transpose_cast_kernel<<<dim3(FD / 32, HD / 32, ED), 256, 0, stream>>>(w1, w1t, HD, FD);
    transpose_cast_kernel<<<dim3(HD / 32, FD / 32, ED), 256, 0, stream>>>(w2, w2t, FD, HD);
    router_kernel<<<NTOK / 4, 256, 0, stream>>>(x, rw, eidx, wgt, xbf);
    scan_kernel<<<1, 1024, 0, stream>>>(eidx, stok, aslot, ecnt);

    // GEMM1: h = gelu(gather(x) @ w1 + b1)  [bf16], 256^2 tiles
    gemm_mfma<HD, FD, FD/256, true>
        <<<8 * (FD/256) * (CAP/256), 512, 0, stream>>>(
        xbf, w1t, b1, stok, ecnt, hbuf);

    // GEMM2: eout = h @ w2 + b2  [fp16, per-slot], 256^2 tiles
    gemm_mfma<FD, HD, HD/256, false>
        <<<8 * (HD/256) * (CAP/256), 512, 0, stream>>>(
        hbuf, w2t, b2, nullptr, ecnt, eout);

    combine_kernel<<<NTOK / 2, 256, 0, stream>>>(eout, eidx, aslot, wgt, out);
}

// Round 9
// 456.281 us; speedup vs baseline: 1.0677x; 1.0620x over previous
//
#include <hip/hip_runtime.h>
#include <hip/hip_bf16.h>

// Problem constants (static per reference)
#define NTOK 16384   // B*T
#define HD   512     // H
#define ED   8       // E experts
#define FD   2048    // F
#define CAP  5120    // capacity per expert
#define NA   32768   // NTOK * K(=2)

typedef __bf16 bf16x8 __attribute__((ext_vector_type(8)));
typedef float  f32x4  __attribute__((ext_vector_type(4)));

// Workspace layout (bytes). Total ~249 MB.
static constexpr size_t OFF_EIDX = 0;                                  // int[NA]
static constexpr size_t OFF_WGT  = 131072;                             // float[NA]
static constexpr size_t OFF_STOK = 262144;                             // int[ED*CAP]
static constexpr size_t OFF_ASLOT= 425984;                             // int[NA]
static constexpr size_t OFF_ECNT = 557056;                             // int[ED]
static constexpr size_t OFF_W2T  = 1u << 20;                           // bf16[ED][HD][FD]
static constexpr size_t OFF_H    = OFF_W2T + (size_t)ED*HD*FD*2;       // bf16[ED][CAP][FD]
static constexpr size_t OFF_W1T  = OFF_H   + (size_t)ED*CAP*FD*2;      // bf16[ED][FD][HD]
static constexpr size_t OFF_XBF  = OFF_W1T + (size_t)ED*FD*HD*2;       // bf16[NTOK][HD]
static constexpr size_t OFF_EOUT = OFF_XBF + (size_t)NTOK*HD*2;        // fp16[ED][CAP][HD]

__device__ __forceinline__ unsigned short f2bf(float f) {
    __bf16 b = (__bf16)f;
    return __builtin_bit_cast(unsigned short, b);
}
__device__ __forceinline__ unsigned short f2h(float f) {
    _Float16 h = (_Float16)f;
    return __builtin_bit_cast(unsigned short, h);
}
__device__ __forceinline__ float h2f(unsigned short u) {
    return (float)__builtin_bit_cast(_Float16, u);
}

// gelu(tanh approx) == v * sigmoid(2*0.79788456*(v + 0.044715 v^3))
// rcp (~1ulp) instead of exact div: invisible after bf16 rounding (R2).
__device__ __forceinline__ float gelu_fast(float v) {
    const float t = v * v;
    const float u = v * fmaf(t, 0.0713548214f, 1.5957691216f);
    const float e = __expf(-u);
    return v * __builtin_amdgcn_rcpf(1.f + e);
}

// ---------------------------------------------------------------------------
// in: [R][C] fp32 (per expert)  ->  out: [C][R] bf16 (per expert)
// ---------------------------------------------------------------------------
__global__ __launch_bounds__(256) void transpose_cast_kernel(
    const float* __restrict__ in, unsigned short* __restrict__ out, int R, int C)
{
    __shared__ unsigned short tile[32][33];
    const int e = blockIdx.z;
    in  += (size_t)e * R * C;
    out += (size_t)e * R * C;
    const int r0 = blockIdx.y * 32, c0 = blockIdx.x * 32;
    const int tr = threadIdx.x >> 3, tc = (threadIdx.x & 7) * 4;
    const float4 v = *(const float4*)(in + (size_t)(r0 + tr) * C + c0 + tc);
    tile[tr][tc + 0] = f2bf(v.x);
    tile[tr][tc + 1] = f2bf(v.y);
    tile[tr][tc + 2] = f2bf(v.z);
    tile[tr][tc + 3] = f2bf(v.w);
    __syncthreads();
    ushort4 o;
    o.x = tile[tc + 0][tr]; o.y = tile[tc + 1][tr];
    o.z = tile[tc + 2][tr]; o.w = tile[tc + 3][tr];
    *(ushort4*)(out + (size_t)(c0 + tr) * R + r0 + tc) = o;
}

// ---------------------------------------------------------------------------
// Router (+ fused x->bf16 cast)
// ---------------------------------------------------------------------------
__global__ __launch_bounds__(256) void router_kernel(
    const float* __restrict__ x, const float* __restrict__ rw,
    int* __restrict__ eidx, float* __restrict__ wgt,
    unsigned short* __restrict__ xbf)
{
    __shared__ float rws[HD * ED];
    const int tid = threadIdx.x;
    for (int i = tid * 4; i < HD * ED; i += 256 * 4)
        *(float4*)(rws + i) = *(const float4*)(rw + i);
    __syncthreads();

    const int wid = tid >> 6, lane = tid & 63;
    const int t = blockIdx.x * 4 + wid;
    const float* xr = x + (size_t)t * HD;

    float acc[ED];
#pragma unroll
    for (int e = 0; e < ED; e++) acc[e] = 0.f;

    float4 xv0 = *(const float4*)(xr + lane * 8);
    float4 xv1 = *(const float4*)(xr + lane * 8 + 4);
    float xv[8] = {xv0.x, xv0.y, xv0.z, xv0.w, xv1.x, xv1.y, xv1.z, xv1.w};

    union { unsigned short us[8]; uint4 v; } pk;
#pragma unroll
    for (int j = 0; j < 8; j++) pk.us[j] = f2bf(xv[j]);
    *(uint4*)(xbf + (size_t)t * HD + lane * 8) = pk.v;

#pragma unroll
    for (int j = 0; j < 8; j++) {
        const int h = lane * 8 + j;
#pragma unroll
        for (int e = 0; e < ED; e++) acc[e] += xv[j] * rws[h * ED + e];
    }
#pragma unroll
    for (int off = 32; off >= 1; off >>= 1) {
#pragma unroll
        for (int e = 0; e < ED; e++) acc[e] += __shfl_down(acc[e], off);
    }
    if (lane == 0) {
        int e0 = 0; float l0 = acc[0];
        for (int e = 1; e < ED; e++) if (acc[e] > l0) { l0 = acc[e]; e0 = e; }
        int e1 = 0; float l1 = -1e30f;
        for (int e = 0; e < ED; e++) {
            if (e == e0) continue;
            if (acc[e] > l1) { l1 = acc[e]; e1 = e; }
        }
        const float ex = expf(l1 - l0);
        const float inv = 1.f / (1.f + ex);
        eidx[t * 2 + 0] = e0;  eidx[t * 2 + 1] = e1;
        wgt [t * 2 + 0] = inv; wgt [t * 2 + 1] = ex * inv;
    }
}

// ---------------------------------------------------------------------------
// Deterministic slot assignment (stable-sort-by-expert), parallel 3-pass scan.
// ---------------------------------------------------------------------------
__global__ __launch_bounds__(1024) void scan_kernel(
    const int* __restrict__ eidx,
    int* __restrict__ stok, int* __restrict__ aslot, int* __restrict__ ecnt)
{
    __shared__ int wcnt[32][16][ED];
    __shared__ int woff[32][16][ED];
    const int tid = threadIdx.x;
    const int lane = tid & 63, wid = tid >> 6;
    const unsigned long long below = (1ull << lane) - 1ull;

    for (int i = tid; i < ED * CAP; i += 1024) stok[i] = -1;

    for (int c = 0; c < NA / 1024; c++) {
        const int e = eidx[c * 1024 + tid];
#pragma unroll
        for (int ee = 0; ee < ED; ee++) {
            unsigned long long m = __ballot(e == ee);
            if (lane == 0) wcnt[c][wid][ee] = __popcll(m);
        }
    }
    __syncthreads();

    if (wid < ED) {
        const int e = wid;
        int carry = 0;
#pragma unroll
        for (int r = 0; r < 8; r++) {
            const int idx = r * 64 + lane;
            const int v = wcnt[idx >> 4][idx & 15][e];
            int s = v;
#pragma unroll
            for (int off = 1; off < 64; off <<= 1) {
                int u = __shfl_up(s, off);
                if (lane >= off) s += u;
            }
            woff[idx >> 4][idx & 15][e] = carry + s - v;
            carry += __shfl(s, 63);
        }
        if (lane == 0) ecnt[e] = carry < CAP ? carry : CAP;
    }
    __syncthreads();

    for (int c = 0; c < NA / 1024; c++) {
        const int a = c * 1024 + tid;
        const int e = eidx[a];
        int myrank = 0;
#pragma unroll
        for (int ee = 0; ee < ED; ee++) {
            unsigned long long m = __ballot(e == ee);
            if (ee == e) myrank = __popcll(m & below);
        }
        const int slot = woff[c][wid][e] + myrank;
        if (slot < CAP) {
            stok[e * CAP + slot] = a >> 1;
            aslot[a] = slot;
        } else {
            aslot[a] = -1;
        }
    }
}

// ---------------------------------------------------------------------------
// MFMA GEMM, R9: REGISTER-STAGED double-buffer, raw asm barrier.
// R8 post-mortem: with global_load_lds, compiler-inserted conservative vmcnt
// waits (LDS-alias tracking) defeat every counted-vmcnt schedule — each
// barrier phase cost ~full memory latency (R5 null, R8 phase≈900-1400cy).
// Fix: stage global->VGPR->ds_write. vmcnt tracking is then PER-REGISTER and
// precise: the wait lands exactly before the ds_write consuming the value,
// one full compute phase after issue; loads stay in flight across barriers;
// ds_read never aliases VMEM. One barrier per K-step (R0's proven shape):
//   [ds_write tile t+1 from regs(t)] [issue loads t+2 -> regs]
//   [COMPUTE tile t: ds_read + MFMA] [lgkmcnt(0); s_barrier]  (no vmcnt drain)
// ds_write XOR-swizzle (same verified mapping as R4's reads): LDS[r][c] =
// G[r][c ^ ((r>>1)&3)] -> write granule classes perfectly balanced (8 lanes /
// 16B-granule = inherent min, conflict-free) and reads measured 0-conflict.
// 32 KB LDS -> 4-5 blocks/CU of TLP covers residual HBM latency (hbuf).
// NOTE (R1): no min-waves floor in __launch_bounds__ (acc spill disaster).
// Operands SWAPPED (mfma(bfv,af)): D col->m, row->n => ushort4 stores (R4).
// G1=true : hout = gelu(gather(x) @ B + bias)  [bf16]
// G1=false: hout = A @ B + bias                [fp16]
// ---------------------------------------------------------------------------
template<int KD, int ND, int NT, bool G1>
__global__ __launch_bounds__(256) void gemm_mfma(
    const unsigned short* __restrict__ Abase,
    const unsigned short* __restrict__ Bt,
    const float* __restrict__ bias,
    const int* __restrict__ stok,
    const int* __restrict__ ecnt,
    unsigned short* __restrict__ hout)
{
    constexpr int BUFE = 128 * 32;            // 4096 elems = 8 KB per buf
    __shared__ __align__(16) unsigned short As[2 * BUFE];
    __shared__ __align__(16) unsigned short Bs[2 * BUFE];

    const int tid = threadIdx.x;
    const int e  = blockIdx.x & 7;            // expert == XCD (id%8 round-robin)
    const int g  = blockIdx.x >> 3;
    const int n0 = (g % NT) * 128;            // n fastest: reuse gathered A in L2
    const int m0 = (g / NT) * 128;

    if (m0 >= ecnt[e]) return;                // padding tile: exit pre-barrier

    const int lane = tid & 63;
    const int wid  = tid >> 6;

    // Staging: thread covers rows r1, r1+64; global 16B chunk q (coalesced).
    const int q  = tid & 3;
    const int r1 = tid >> 2;                  // 0..63
    const int r2 = r1 + 64;

    size_t ai1, ai2;
    if constexpr (G1) {
        const int t1 = stok[e * CAP + m0 + r1];
        const int t2 = stok[e * CAP + m0 + r2];
        ai1 = (size_t)(t1 >= 0 ? t1 : 0);     // dropped -> row 0 (never read back)
        ai2 = (size_t)(t2 >= 0 ? t2 : 0);
    } else {
        ai1 = (size_t)(e * CAP + m0 + r1);
        ai2 = (size_t)(e * CAP + m0 + r2);
    }
    const unsigned short* arow1 = Abase + ai1 * KD + q * 8;
    const unsigned short* arow2 = Abase + ai2 * KD + q * 8;
    const unsigned short* brow1 = Bt + ((size_t)e * ND + n0 + r1) * KD + q * 8;
    const unsigned short* brow2 = Bt + ((size_t)e * ND + n0 + r2) * KD + q * 8;

    // Swizzled ds_write offsets: LDS chunk c = q ^ ((r>>1)&3); same class for
    // r2 = r1+64. Write granule classes balanced (conflict-free).
    const int cSw = q ^ ((r1 >> 1) & 3);
    const int oW1 = r1 * 32 + cSw * 8;
    const int oW2 = r2 * 32 + cSw * 8;

    // Fragment read bases (R4-verified, 0 conflicts): read LDS[row][xq] where
    // xq = quad ^ ((l15>>1)&3)  ->  G[row][quad].
    const int wrow = (wid & 1) * 64;
    const int wcol = (wid >> 1) * 64;
    const int l15  = lane & 15;
    const int quad = lane >> 4;
    const int xq   = quad ^ ((l15 >> 1) & 3);
    const int fA   = (wrow + l15) * 32 + xq * 8;
    const int fB   = (wcol + l15) * 32 + xq * 8;

    f32x4 acc[4][4];
#pragma unroll
    for (int i = 0; i < 4; i++)
#pragma unroll
        for (int j = 0; j < 4; j++) acc[i][j] = (f32x4)0.f;

// Swapped-operand MFMA: D = bfv x af -> col(lane&15) indexes m, row indexes n.
#define COMPUTE(PBUF)                                                          \
    {                                                                          \
        const unsigned short* Ab = As + (PBUF) * BUFE;                         \
        const unsigned short* Bb = Bs + (PBUF) * BUFE;                         \
        bf16x8 af[4], bfv[4];                                                  \
        _Pragma("unroll")                                                      \
        for (int i = 0; i < 4; i++) af[i]  = *(const bf16x8*)(Ab + fA + i * 512); \
        _Pragma("unroll")                                                      \
        for (int j = 0; j < 4; j++) bfv[j] = *(const bf16x8*)(Bb + fB + j * 512); \
        _Pragma("unroll")                                                      \
        for (int i = 0; i < 4; i++)                                            \
            _Pragma("unroll")                                                  \
            for (int j = 0; j < 4; j++)                                        \
                acc[i][j] = __builtin_amdgcn_mfma_f32_16x16x32_bf16(           \
                    bfv[j], af[i], acc[i][j], 0, 0, 0);                        \
    }

// lgkm-only barrier: ds_writes visible + my ds_reads done; NO vmcnt drain —
// in-flight global->reg loads survive the barrier (per-register tracking).
#define LBAR asm volatile("s_waitcnt lgkmcnt(0)\n\ts_barrier" ::: "memory")

    // Prologue: tile 0 -> regs -> buf0; tile 1 -> regs (in flight).
    float4 ra1 = *(const float4*)(arow1);
    float4 ra2 = *(const float4*)(arow2);
    float4 rb1 = *(const float4*)(brow1);
    float4 rb2 = *(const float4*)(brow2);
    *(float4*)(&As[oW1]) = ra1;
    *(float4*)(&As[oW2]) = ra2;
    *(float4*)(&Bs[oW1]) = rb1;
    *(float4*)(&Bs[oW2]) = rb2;
    if (32 < KD) {
        ra1 = *(const float4*)(arow1 + 32);
        ra2 = *(const float4*)(arow2 + 32);
        rb1 = *(const float4*)(brow1 + 32);
        rb2 = *(const float4*)(brow2 + 32);
    }
    LBAR;

    int rbuf = 0;
    for (int kc = 0; kc < KD; kc += 32) {
        const int wb = (rbuf ^ 1) * BUFE;
        if (kc + 32 < KD) {
            // ds_write tile kc+32 (vmcnt wait: loads issued one iteration ago)
            *(float4*)(&As[wb + oW1]) = ra1;
            *(float4*)(&As[wb + oW2]) = ra2;
            *(float4*)(&Bs[wb + oW1]) = rb1;
            *(float4*)(&Bs[wb + oW2]) = rb2;
            if (kc + 64 < KD) {
                ra1 = *(const float4*)(arow1 + kc + 64);
                ra2 = *(const float4*)(arow2 + kc + 64);
                rb1 = *(const float4*)(brow1 + kc + 64);
                rb2 = *(const float4*)(brow2 + kc + 64);
            }
        }
        COMPUTE(rbuf);
        LBAR;
        rbuf ^= 1;
    }
#undef COMPUTE
#undef LBAR

    // Epilogue (transposed D): m = wrow + i*16 + l15, n = wcol + j*16 + quad*4
    // + g2 -> 4 consecutive n per (i,j) -> one ushort4 store each.
#pragma unroll
    for (int i = 0; i < 4; i++) {
        unsigned short* hrow = hout
            + ((size_t)e * CAP + m0 + wrow + i * 16 + l15) * ND
            + n0 + wcol + quad * 4;
#pragma unroll
        for (int j = 0; j < 4; j++) {
            const float4 b4 = *(const float4*)(
                bias + (size_t)e * ND + n0 + wcol + j * 16 + quad * 4);
            const float v0 = acc[i][j][0] + b4.x;
            const float v1 = acc[i][j][1] + b4.y;
            const float v2 = acc[i][j][2] + b4.z;
            const float v3 = acc[i][j][3] + b4.w;
            ushort4 o;
            if constexpr (G1) {
                o.x = f2bf(gelu_fast(v0)); o.y = f2bf(gelu_fast(v1));
                o.z = f2bf(gelu_fast(v2)); o.w = f2bf(gelu_fast(v3));
            } else {
                o.x = f2h(v0); o.y = f2h(v1); o.z = f2h(v2); o.w = f2h(v3);
            }
            *(ushort4*)(hrow + j * 16) = o;
        }
    }
}

// ---------------------------------------------------------------------------
// Combine: out[t] = sum_k wgt[t,k] * eout[eidx[t,k], aslot[t,k]]
// ---------------------------------------------------------------------------
__global__ __launch_bounds__(256) void combine_kernel(
    const unsigned short* __restrict__ eout,
    const int* __restrict__ eidx, const int* __restrict__ aslot,
    const float* __restrict__ wgt, float* __restrict__ out)
{
    const int tid = threadIdx.x;
    const int t  = blockIdx.x * 2 + (tid >> 7);
    const int h0 = (tid & 127) * 4;
    float r0 = 0.f, r1 = 0.f, r2 = 0.f, r3 = 0.f;
#pragma unroll
    for (int k = 0; k < 2; k++) {
        const int a = t * 2 + k;
        const int s = aslot[a];
        if (s >= 0) {
            const float w = wgt[a];
            const int e = eidx[a];
            const ushort4 v = *(const ushort4*)(eout + ((size_t)e * CAP + s) * HD + h0);
            r0 += w * h2f(v.x); r1 += w * h2f(v.y);
            r2 += w * h2f(v.z); r3 += w * h2f(v.w);
        }
    }
    float4 o; o.x = r0; o.y = r1; o.z = r2; o.w = r3;
    *(float4*)(out + (size_t)t * HD + h0) = o;
}

extern "C" void kernel_launch(void* const* d_in, const int* in_sizes, int n_in,
                              void* d_out, int out_size, void* d_ws, size_t ws_size,
                              hipStream_t stream)
{
    const float* x  = (const float*)d_in[0];
    const float* rw = (const float*)d_in[1];
    const float* w1 = (const float*)d_in[2];
    const float* b1 = (const float*)d_in[3];
    const float* w2 = (const float*)d_in[4];
    const float* b2 = (const float*)d_in[5];
    float* out = (float*)d_out;

    char* ws = (char*)d_ws;
    int*   eidx  = (int*)  (ws + OFF_EIDX);
    float* wgt   = (float*)(ws + OFF_WGT);
    int*   stok  = (int*)  (ws + OFF_STOK);
    int*   aslot = (int*)  (ws + OFF_ASLOT);
    int*   ecnt  = (int*)  (ws + OFF_ECNT);
    unsigned short* w2t  = (unsigned short*)(ws + OFF_W2T);
    unsigned short* hbuf = (unsigned short*)(ws + OFF_H);
    unsigned short* w1t  = (unsigned short*)(ws + OFF_W1T);
    unsigned short* xbf  = (unsigned short*)(ws + OFF_XBF);
    unsigned short* eout = (unsigned short*)(ws + OFF_EOUT);

    transpose_cast_kernel<<<dim3(FD / 32, HD / 32, ED), 256, 0, stream>>>(w1, w1t, HD, FD);
    transpose_cast_kernel<<<dim3(HD / 32, FD / 32, ED), 256, 0, stream>>>(w2, w2t, FD, HD);
    router_kernel<<<NTOK / 4, 256, 0, stream>>>(x, rw, eidx, wgt, xbf);
    scan_kernel<<<1, 1024, 0, stream>>>(eidx, stok, aslot, ecnt);

    // GEMM1: h = gelu(gather(x) @ w1 + b1)  [bf16], 128^2 tiles
    gemm_mfma<HD, FD, FD/128, true>
        <<<8 * (FD/128) * (CAP/128), 256, 0, stream>>>(
        xbf, w1t, b1, stok, ecnt, hbuf);

    // GEMM2: eout = h @ w2 + b2  [fp16, per-slot], 128^2 tiles
    gemm_mfma<FD, HD, HD/128, false>
        <<<8 * (HD/128) * (CAP/128), 256, 0, stream>>>(
        hbuf, w2t, b2, nullptr, ecnt, eout);

    combine_kernel<<<NTOK / 2, 256, 0, stream>>>(eout, eidx, aslot, wgt, out);
}